// Round 3
// baseline (60.017 us; speedup 1.0000x reference)
//
#include <hip/hip_runtime.h>
#include <hip/hip_bf16.h>

// Problem constants: B=32, T=256, N=1024 -> R = 8192 rows, K = N-1 = 1023 (padded to 1024)
// alpha = 0.5, b[m] = sqrt(m+1)-sqrt(m), coef = sqrt(1023)/Gamma(1.5)
#define COEF 36.090511f
#define INV_COUNT (1.0f / 8388608.0f)   // 1 / (32*256*1024)

typedef __attribute__((ext_vector_type(4))) float f32x4;
typedef __attribute__((ext_vector_type(8))) __bf16 bf16x8;

typedef const __attribute__((address_space(1))) unsigned int* gas_ptr;
typedef __attribute__((address_space(3))) unsigned int* las_ptr;

__device__ __forceinline__ void load_lds16(const void* g, void* l) {
  __builtin_amdgcn_global_load_lds((gas_ptr)g, (las_ptr)l, 16, 0, 0);
}

// Mt[i][j] = b[i-j] for j <= i, else 0.  (transposed Toeplitz so B-tiles are [col][k] row-major)
__global__ void build_mt(__hip_bfloat16* __restrict__ Mt) {
  int idx = blockIdx.x * 256 + threadIdx.x;   // 1024*1024 elements
  int i = idx >> 10;
  int j = idx & 1023;
  int m = i - j;
  float v = (m >= 0) ? (sqrtf((float)(m + 1)) - sqrtf((float)m)) : 0.f;
  Mt[idx] = __float2bfloat16(v);
}

// du (bf16, padded col 1023 = 0); per-block partials (no same-address atomics).
__global__ void prep(const float* __restrict__ up, const float* __restrict__ utr,
                     __hip_bfloat16* __restrict__ du,
                     float* __restrict__ dpart, float* __restrict__ ppart) {
  const int r = blockIdx.x;       // 8192 rows
  const int t = threadIdx.x;      // 256 threads
  const int j0 = t * 4;
  const float* rowp = up + (size_t)r * 1024;

  f32x4 a = *(const f32x4*)(rowp + j0);
  float a4 = (t < 255) ? rowp[j0 + 4] : 0.f;
  f32x4 b = *(const f32x4*)(utr + (size_t)r * 1024 + j0);

  float d0 = a[1] - a[0];
  float d1 = a[2] - a[1];
  float d2 = a[3] - a[2];
  float d3 = (t < 255) ? (a4 - a[3]) : 0.f;   // du[1023] = 0 pad

  union { ushort4 u4; __hip_bfloat16 h[4]; } pk;
  pk.h[0] = __float2bfloat16(d0);
  pk.h[1] = __float2bfloat16(d1);
  pk.h[2] = __float2bfloat16(d2);
  pk.h[3] = __float2bfloat16(d3);
  *(ushort4*)(du + (size_t)r * 1024 + j0) = pk.u4;

  float e0 = a[0] - b[0], e1 = a[1] - b[1], e2 = a[2] - b[2], e3 = a[3] - b[3];
  float dsum = e0 * e0 + e1 * e1 + e2 * e2 + e3 * e3;

#pragma unroll
  for (int off = 32; off > 0; off >>= 1) dsum += __shfl_down(dsum, off, 64);
  __shared__ float ws4[4];
  const int lane = t & 63, w = t >> 6;
  if (lane == 0) ws4[w] = dsum;
  __syncthreads();
  if (t == 0) {
    dpart[r] = ws4[0] + ws4[1] + ws4[2] + ws4[3];
    ppart[r] = d0 * d0;   // physics residual at n=0: u_t = du[r,0], frac_lap[0] = 0
  }
}

// Y[r,i] = sum_j du[r,j] * b[i-j]; fused epilogue: resid = u_t - COEF*Y, accumulate resid^2.
// 128x128 tile, BK=64, 4 waves (2x2 of 64x64), double-buffered LDS.
// LDS layout [128 rows][64 k] with 16B-quad XOR swizzle: phys_quad = quad ^ (row&7).
// Row stride = 128B = 32 banks -> each 16-lane ds_read_b128 group covers all banks (2-way, free).
// Swizzle applied BOTH on global source col (pre-swizzle; global_load_lds dest is linear)
// and on ds_read address (rule: both-sides-or-neither).
__launch_bounds__(256, 2)
__global__ void gemm(const __hip_bfloat16* __restrict__ du,
                     const __hip_bfloat16* __restrict__ Mt,
                     float* __restrict__ gpart) {
  __shared__ __hip_bfloat16 sA[2][8192];   // [128][64]
  __shared__ __hip_bfloat16 sB[2][8192];
  __shared__ float wsum[4];

  const int t = threadIdx.x;
  const int w = t >> 6;
  const int lane = t & 63;

  // triangular load-balance: pair cb c2 with 7-c2 so sequential block pairs have uniform work
  const int bid = blockIdx.x;      // 0..511
  const int half = bid >> 8;
  const int idx = bid & 255;
  const int rb = idx >> 2;         // 0..63
  const int c2 = idx & 3;
  const int cb = half ? (7 - c2) : c2;
  const int row0 = rb * 128;
  const int col0 = cb * 128;
  const int nkb = 2 * (cb + 1);    // K-blocks of 64 (triangular skip)

  const f32x4 vzero = {0.f, 0.f, 0.f, 0.f};
  f32x4 acc[4][4];
#pragma unroll
  for (int i = 0; i < 4; i++)
#pragma unroll
    for (int j = 0; j < 4; j++) acc[i][j] = vzero;

  // staging: 4 lines per matrix, each line = 256 threads x 16B = 32 rows of 128B.
  // thread t covers (row_in_line = t>>3, phys quad p = t&7); source logical quad = p ^ (row&7).
  const int srow = t >> 3;                       // 0..31
  const int scol = ((t & 7) ^ (srow & 7)) * 8;   // pre-swizzled source col (elements)
  const __hip_bfloat16* gA0 = du + (size_t)(row0 + srow) * 1024 + scol;
  const __hip_bfloat16* gB0 = Mt + (size_t)(col0 + srow) * 1024 + scol;

  auto stage = [&](int buf, int kb) {
    const int kc = kb * 64;
#pragma unroll
    for (int l = 0; l < 4; l++)
      load_lds16(gA0 + (size_t)l * 32 * 1024 + kc, (void*)&sA[buf][l * 2048 + t * 8]);
#pragma unroll
    for (int l = 0; l < 4; l++)
      load_lds16(gB0 + (size_t)l * 32 * 1024 + kc, (void*)&sB[buf][l * 2048 + t * 8]);
  };

  const int wm = w >> 1, wn = w & 1;
  const int frow = lane & 15;
  const int g4 = lane >> 4;              // k-chunk group 0..3
  const int ph0 = g4 ^ (frow & 7);       // ksub=0 physical quad (row&7 == frow&7)

  auto compute = [&](int buf) {
#pragma unroll
    for (int ksub = 0; ksub < 2; ksub++) {
      const int ph = ph0 ^ (ksub << 2);  // ksub=1 -> quad+4
      bf16x8 aF[4], bF[4];
#pragma unroll
      for (int fm = 0; fm < 4; fm++)
        aF[fm] = *(const bf16x8*)&sA[buf][(wm * 64 + fm * 16 + frow) * 64 + ph * 8];
#pragma unroll
      for (int fn = 0; fn < 4; fn++)
        bF[fn] = *(const bf16x8*)&sB[buf][(wn * 64 + fn * 16 + frow) * 64 + ph * 8];
#pragma unroll
      for (int fm = 0; fm < 4; fm++)
#pragma unroll
        for (int fn = 0; fn < 4; fn++)
          acc[fm][fn] = __builtin_amdgcn_mfma_f32_16x16x32_bf16(aF[fm], bF[fn], acc[fm][fn], 0, 0, 0);
    }
  };

  stage(0, 0);
  for (int kb = 0; kb < nkb; kb++) {
    __syncthreads();                            // tile kb resident (barrier drains vmcnt)
    if (kb + 1 < nkb) stage((kb + 1) & 1, kb + 1);
    compute(kb & 1);
  }

  // fused epilogue: C/D layout col = lane&15, row = (lane>>4)*4 + reg  [HW-verified]
  float psum = 0.f;
  const int rbase = row0 + wm * 64 + (lane >> 4) * 4;
  const int ibase = col0 + wn * 64 + frow;
#pragma unroll
  for (int fm = 0; fm < 4; fm++) {
#pragma unroll
    for (int fn = 0; fn < 4; fn++) {
      const int icol = ibase + fn * 16;        // du index i; output position n = i+1
      if (icol < 1023) {
#pragma unroll
        for (int reg = 0; reg < 4; reg++) {
          const int r = rbase + fm * 16 + reg;
          float frac = COEF * acc[fm][fn][reg];
          float dui = __bfloat162float(du[(size_t)r * 1024 + icol]);
          float ut;
          if (icol == 1022) {
            ut = dui;                           // n = N-1 edge: u_t = du[N-2]
          } else {
            float dui1 = __bfloat162float(du[(size_t)r * 1024 + icol + 1]);
            ut = 0.5f * (dui + dui1);           // central difference
          }
          float res = ut - frac;
          psum += res * res;
        }
      }
    }
  }

#pragma unroll
  for (int off = 32; off > 0; off >>= 1) psum += __shfl_down(psum, off, 64);
  if (lane == 0) wsum[w] = psum;
  __syncthreads();
  if (t == 0) gpart[bid] = wsum[0] + wsum[1] + wsum[2] + wsum[3];
}

// Single-block tree reduction of all partials -> 3 outputs.
__global__ void finalize(const float* __restrict__ dpart, const float* __restrict__ ppart,
                         const float* __restrict__ gpart, float* __restrict__ out) {
  const int t = threadIdx.x;    // 256 threads
  float ds = 0.f, ps = 0.f;
  for (int i = t; i < 8192; i += 256) { ds += dpart[i]; ps += ppart[i]; }
  for (int i = t; i < 512; i += 256) ps += gpart[i];

#pragma unroll
  for (int off = 32; off > 0; off >>= 1) {
    ds += __shfl_down(ds, off, 64);
    ps += __shfl_down(ps, off, 64);
  }
  __shared__ float sd[4], sp[4];
  const int lane = t & 63, w = t >> 6;
  if (lane == 0) { sd[w] = ds; sp[w] = ps; }
  __syncthreads();
  if (t == 0) {
    float data = (sd[0] + sd[1] + sd[2] + sd[3]) * INV_COUNT;
    float phys = (sp[0] + sp[1] + sp[2] + sp[3]) * INV_COUNT;
    out[0] = data + 0.1f * phys;
    out[1] = data;
    out[2] = phys;
  }
}

extern "C" void kernel_launch(void* const* d_in, const int* in_sizes, int n_in,
                              void* d_out, int out_size, void* d_ws, size_t ws_size,
                              hipStream_t stream) {
  const float* u_pred = (const float*)d_in[0];
  const float* u_true = (const float*)d_in[1];
  float* out = (float*)d_out;

  char* ws = (char*)d_ws;
  float* dpart = (float*)ws;                                    // 8192 floats (32 KiB)
  float* ppart = (float*)(ws + 32768);                          // 8192 floats (32 KiB)
  float* gpart = (float*)(ws + 65536);                          // 512 floats (2 KiB)
  __hip_bfloat16* Mt = (__hip_bfloat16*)(ws + 131072);          // 1024*1024*2 = 2 MiB
  __hip_bfloat16* du = (__hip_bfloat16*)(ws + 131072 + 2097152);// 8192*1024*2 = 16 MiB

  build_mt<<<4096, 256, 0, stream>>>(Mt);
  prep<<<8192, 256, 0, stream>>>(u_pred, u_true, du, dpart, ppart);
  gemm<<<512, 256, 0, stream>>>(du, Mt, gpart);
  finalize<<<1, 256, 0, stream>>>(dpart, ppart, gpart, out);
}

// Round 4
// 55.940 us; speedup vs baseline: 1.0729x; 1.0729x over previous
//
#include <hip/hip_runtime.h>
#include <hip/hip_bf16.h>

// Problem constants: B=32, T=256, N=1024 -> R = 8192 rows, K = N-1 = 1023 (padded to 1024)
// alpha = 0.5, b[m] = sqrt(m+1)-sqrt(m), coef = sqrt(1023)/Gamma(1.5)
#define COEF 36.090511f
#define INV_COUNT (1.0f / 8388608.0f)   // 1 / (32*256*1024)

typedef __attribute__((ext_vector_type(4))) float f32x4;
typedef __attribute__((ext_vector_type(8))) __bf16 bf16x8;

typedef const __attribute__((address_space(1))) unsigned int* gas_ptr;
typedef __attribute__((address_space(3))) unsigned int* las_ptr;

__device__ __forceinline__ void load_lds16(const void* g, void* l) {
  __builtin_amdgcn_global_load_lds((gas_ptr)g, (las_ptr)l, 16, 0, 0);
}

// prep blocks 0..8191: du (bf16, padded col 1023 = 0) + per-row partials.
// blocks 8192..9215: build Mt[i][j] = b[i-j] (transposed Toeplitz), one row each.
__global__ void prep(const float* __restrict__ up, const float* __restrict__ utr,
                     __hip_bfloat16* __restrict__ du, __hip_bfloat16* __restrict__ Mt,
                     float* __restrict__ dpart, float* __restrict__ ppart) {
  const int t = threadIdx.x;      // 256 threads
  if (blockIdx.x >= 8192) {
    const int i = blockIdx.x - 8192;    // Mt row 0..1023
    const int j0 = t * 4;
    union { ushort4 u4; __hip_bfloat16 h[4]; } pk;
#pragma unroll
    for (int e = 0; e < 4; e++) {
      int m = i - (j0 + e);
      float v = (m >= 0) ? (sqrtf((float)(m + 1)) - sqrtf((float)m)) : 0.f;
      pk.h[e] = __float2bfloat16(v);
    }
    *(ushort4*)(Mt + (size_t)i * 1024 + j0) = pk.u4;
    return;
  }

  const int r = blockIdx.x;       // 8192 rows
  const int j0 = t * 4;
  const float* rowp = up + (size_t)r * 1024;

  f32x4 a = *(const f32x4*)(rowp + j0);
  float a4 = (t < 255) ? rowp[j0 + 4] : 0.f;
  f32x4 b = *(const f32x4*)(utr + (size_t)r * 1024 + j0);

  float d0 = a[1] - a[0];
  float d1 = a[2] - a[1];
  float d2 = a[3] - a[2];
  float d3 = (t < 255) ? (a4 - a[3]) : 0.f;   // du[1023] = 0 pad

  union { ushort4 u4; __hip_bfloat16 h[4]; } pk;
  pk.h[0] = __float2bfloat16(d0);
  pk.h[1] = __float2bfloat16(d1);
  pk.h[2] = __float2bfloat16(d2);
  pk.h[3] = __float2bfloat16(d3);
  *(ushort4*)(du + (size_t)r * 1024 + j0) = pk.u4;

  float e0 = a[0] - b[0], e1 = a[1] - b[1], e2 = a[2] - b[2], e3 = a[3] - b[3];
  float dsum = e0 * e0 + e1 * e1 + e2 * e2 + e3 * e3;

#pragma unroll
  for (int off = 32; off > 0; off >>= 1) dsum += __shfl_down(dsum, off, 64);
  __shared__ float ws4[4];
  const int lane = t & 63, w = t >> 6;
  if (lane == 0) ws4[w] = dsum;
  __syncthreads();
  if (t == 0) {
    dpart[r] = ws4[0] + ws4[1] + ws4[2] + ws4[3];
    ppart[r] = d0 * d0;   // physics residual at n=0: u_t = du[r,0], frac_lap[0] = 0
  }
}

// Y[r,i] = sum_j du[r,j] * b[i-j]; fused epilogue: resid = u_t - COEF*Y, accumulate resid^2.
// 128x128 tile, BK=64, 4 waves (2x2 of 64x64), double-buffered LDS, XOR-swizzled quads.
// K-loop uses raw s_barrier + COUNTED s_waitcnt vmcnt(8): next tile's 8 global_load_lds
// stay in flight across the barrier (T4); only the last iteration drains to 0.
__launch_bounds__(256, 2)
__global__ void gemm(const __hip_bfloat16* __restrict__ du,
                     const __hip_bfloat16* __restrict__ Mt,
                     float* __restrict__ gpart) {
  __shared__ __hip_bfloat16 sA[2][8192];   // [128][64], quad-swizzled
  __shared__ __hip_bfloat16 sB[2][8192];
  __shared__ float wsum[4];

  const int t = threadIdx.x;
  const int w = t >> 6;
  const int lane = t & 63;

  // triangular load-balance: pair cb c2 with 7-c2 so each CU gets light+heavy block
  const int bid = blockIdx.x;      // 0..511
  const int half = bid >> 8;
  const int idx = bid & 255;
  const int rb = idx >> 2;         // 0..63
  const int c2 = idx & 3;
  const int cb = half ? (7 - c2) : c2;
  const int row0 = rb * 128;
  const int col0 = cb * 128;
  const int nkb = 2 * (cb + 1);    // K-blocks of 64 (triangular skip)

  const f32x4 vzero = {0.f, 0.f, 0.f, 0.f};
  f32x4 acc[4][4];
#pragma unroll
  for (int i = 0; i < 4; i++)
#pragma unroll
    for (int j = 0; j < 4; j++) acc[i][j] = vzero;

  // staging: thread t covers (row = t>>3, phys quad = t&7); source quad = phys ^ (row&7)
  const int srow = t >> 3;                       // 0..31
  const int scol = ((t & 7) ^ (srow & 7)) * 8;   // pre-swizzled source col (elements)
  const __hip_bfloat16* gA0 = du + (size_t)(row0 + srow) * 1024 + scol;
  const __hip_bfloat16* gB0 = Mt + (size_t)(col0 + srow) * 1024 + scol;

  auto stage = [&](int buf, int kb) {
    const int kc = kb * 64;
#pragma unroll
    for (int l = 0; l < 4; l++)
      load_lds16(gA0 + (size_t)l * 32 * 1024 + kc, (void*)&sA[buf][l * 2048 + t * 8]);
#pragma unroll
    for (int l = 0; l < 4; l++)
      load_lds16(gB0 + (size_t)l * 32 * 1024 + kc, (void*)&sB[buf][l * 2048 + t * 8]);
  };

  const int wm = w >> 1, wn = w & 1;
  const int frow = lane & 15;
  const int g4 = lane >> 4;              // logical k-quad 0..3
  const int ph0 = g4 ^ (frow & 7);       // ksub=0 physical quad

  auto compute = [&](int buf) {
#pragma unroll
    for (int ksub = 0; ksub < 2; ksub++) {
      const int ph = ph0 ^ (ksub << 2);  // ksub=1 -> logical quad +4
      bf16x8 aF[4], bF[4];
#pragma unroll
      for (int fm = 0; fm < 4; fm++)
        aF[fm] = *(const bf16x8*)&sA[buf][(wm * 64 + fm * 16 + frow) * 64 + ph * 8];
#pragma unroll
      for (int fn = 0; fn < 4; fn++)
        bF[fn] = *(const bf16x8*)&sB[buf][(wn * 64 + fn * 16 + frow) * 64 + ph * 8];
#pragma unroll
      for (int fm = 0; fm < 4; fm++)
#pragma unroll
        for (int fn = 0; fn < 4; fn++)
          acc[fm][fn] = __builtin_amdgcn_mfma_f32_16x16x32_bf16(aF[fm], bF[fn], acc[fm][fn], 0, 0, 0);
    }
  };

  stage(0, 0);
  for (int kb = 0; kb < nkb; kb++) {
    // BARRIER A: all waves done computing kb-1 (done reading buf kb+1&1) -> safe to overwrite
    asm volatile("" ::: "memory");
    __builtin_amdgcn_s_barrier();
    asm volatile("" ::: "memory");
    if (kb + 1 < nkb) {
      stage((kb + 1) & 1, kb + 1);                    // 8 loads in flight across barrier
      asm volatile("s_waitcnt vmcnt(8)" ::: "memory"); // cur tile's 8 (from kb-1) complete
    } else {
      asm volatile("s_waitcnt vmcnt(0)" ::: "memory"); // last tile: drain
    }
    // BARRIER B: every wave's cur loads complete
    __builtin_amdgcn_s_barrier();
    asm volatile("" ::: "memory");
    compute(kb & 1);
  }

  // fused epilogue: C/D layout col = lane&15, row = (lane>>4)*4 + reg  [HW-verified]
  float psum = 0.f;
  const int rbase = row0 + wm * 64 + (lane >> 4) * 4;
  const int ibase = col0 + wn * 64 + frow;
#pragma unroll
  for (int fm = 0; fm < 4; fm++) {
#pragma unroll
    for (int fn = 0; fn < 4; fn++) {
      const int icol = ibase + fn * 16;        // du index i; output position n = i+1
      if (icol < 1023) {
#pragma unroll
        for (int reg = 0; reg < 4; reg++) {
          const int r = rbase + fm * 16 + reg;
          float frac = COEF * acc[fm][fn][reg];
          float dui = __bfloat162float(du[(size_t)r * 1024 + icol]);
          float ut;
          if (icol == 1022) {
            ut = dui;                           // n = N-1 edge: u_t = du[N-2]
          } else {
            float dui1 = __bfloat162float(du[(size_t)r * 1024 + icol + 1]);
            ut = 0.5f * (dui + dui1);           // central difference
          }
          float res = ut - frac;
          psum += res * res;
        }
      }
    }
  }

#pragma unroll
  for (int off = 32; off > 0; off >>= 1) psum += __shfl_down(psum, off, 64);
  if (lane == 0) wsum[w] = psum;
  __syncthreads();
  if (t == 0) gpart[bid] = wsum[0] + wsum[1] + wsum[2] + wsum[3];
}

// Single-block tree reduction of all partials -> 3 outputs.
__global__ void finalize(const float* __restrict__ dpart, const float* __restrict__ ppart,
                         const float* __restrict__ gpart, float* __restrict__ out) {
  const int t = threadIdx.x;    // 256 threads
  float ds = 0.f, ps = 0.f;
  for (int i = t; i < 8192; i += 256) { ds += dpart[i]; ps += ppart[i]; }
  for (int i = t; i < 512; i += 256) ps += gpart[i];

#pragma unroll
  for (int off = 32; off > 0; off >>= 1) {
    ds += __shfl_down(ds, off, 64);
    ps += __shfl_down(ps, off, 64);
  }
  __shared__ float sd[4], sp[4];
  const int lane = t & 63, w = t >> 6;
  if (lane == 0) { sd[w] = ds; sp[w] = ps; }
  __syncthreads();
  if (t == 0) {
    float data = (sd[0] + sd[1] + sd[2] + sd[3]) * INV_COUNT;
    float phys = (sp[0] + sp[1] + sp[2] + sp[3]) * INV_COUNT;
    out[0] = data + 0.1f * phys;
    out[1] = data;
    out[2] = phys;
  }
}

extern "C" void kernel_launch(void* const* d_in, const int* in_sizes, int n_in,
                              void* d_out, int out_size, void* d_ws, size_t ws_size,
                              hipStream_t stream) {
  const float* u_pred = (const float*)d_in[0];
  const float* u_true = (const float*)d_in[1];
  float* out = (float*)d_out;

  char* ws = (char*)d_ws;
  float* dpart = (float*)ws;                                    // 8192 floats (32 KiB)
  float* ppart = (float*)(ws + 32768);                          // 8192 floats (32 KiB)
  float* gpart = (float*)(ws + 65536);                          // 512 floats (2 KiB)
  __hip_bfloat16* Mt = (__hip_bfloat16*)(ws + 131072);          // 1024*1024*2 = 2 MiB
  __hip_bfloat16* du = (__hip_bfloat16*)(ws + 131072 + 2097152);// 8192*1024*2 = 16 MiB

  prep<<<9216, 256, 0, stream>>>(u_pred, u_true, du, Mt, dpart, ppart);
  gemm<<<512, 256, 0, stream>>>(du, Mt, gpart);
  finalize<<<1, 256, 0, stream>>>(dpart, ppart, gpart, out);
}

// Round 5
// 51.242 us; speedup vs baseline: 1.1712x; 1.0917x over previous
//
#include <hip/hip_runtime.h>
#include <hip/hip_bf16.h>

// Problem constants: B=32, T=256, N=1024 -> R = 8192 rows, K = N-1 = 1023 (padded to 1024)
// alpha = 0.5, b[m] = sqrt(m+1)-sqrt(m), coef = sqrt(1023)/Gamma(1.5)
#define COEF 36.090511f
#define INV_COUNT (1.0f / 8388608.0f)   // 1 / (32*256*1024)

typedef __attribute__((ext_vector_type(4))) float f32x4;
typedef __attribute__((ext_vector_type(8))) __bf16 bf16x8;

typedef const __attribute__((address_space(1))) unsigned int* gas_ptr;
typedef __attribute__((address_space(3))) unsigned int* las_ptr;

__device__ __forceinline__ void load_lds16(const void* g, void* l) {
  __builtin_amdgcn_global_load_lds((gas_ptr)g, (las_ptr)l, 16, 0, 0);
}

// prep blocks 0..8191: du (bf16, padded col 1023 = 0) + per-row partials.
// blocks 8192..9215: build Mt[i][j] = b[i-j] (transposed Toeplitz), one row each.
__global__ void prep(const float* __restrict__ up, const float* __restrict__ utr,
                     __hip_bfloat16* __restrict__ du, __hip_bfloat16* __restrict__ Mt,
                     float* __restrict__ dpart, float* __restrict__ ppart) {
  const int t = threadIdx.x;      // 256 threads
  if (blockIdx.x >= 8192) {
    const int i = blockIdx.x - 8192;    // Mt row 0..1023
    const int j0 = t * 4;
    union { ushort4 u4; __hip_bfloat16 h[4]; } pk;
#pragma unroll
    for (int e = 0; e < 4; e++) {
      int m = i - (j0 + e);
      float v = (m >= 0) ? (sqrtf((float)(m + 1)) - sqrtf((float)m)) : 0.f;
      pk.h[e] = __float2bfloat16(v);
    }
    *(ushort4*)(Mt + (size_t)i * 1024 + j0) = pk.u4;
    return;
  }

  const int r = blockIdx.x;       // 8192 rows
  const int j0 = t * 4;
  const float* rowp = up + (size_t)r * 1024;

  f32x4 a = *(const f32x4*)(rowp + j0);
  float a4 = (t < 255) ? rowp[j0 + 4] : 0.f;
  f32x4 b = *(const f32x4*)(utr + (size_t)r * 1024 + j0);

  float d0 = a[1] - a[0];
  float d1 = a[2] - a[1];
  float d2 = a[3] - a[2];
  float d3 = (t < 255) ? (a4 - a[3]) : 0.f;   // du[1023] = 0 pad

  union { ushort4 u4; __hip_bfloat16 h[4]; } pk;
  pk.h[0] = __float2bfloat16(d0);
  pk.h[1] = __float2bfloat16(d1);
  pk.h[2] = __float2bfloat16(d2);
  pk.h[3] = __float2bfloat16(d3);
  *(ushort4*)(du + (size_t)r * 1024 + j0) = pk.u4;

  float e0 = a[0] - b[0], e1 = a[1] - b[1], e2 = a[2] - b[2], e3 = a[3] - b[3];
  float dsum = e0 * e0 + e1 * e1 + e2 * e2 + e3 * e3;

#pragma unroll
  for (int off = 32; off > 0; off >>= 1) dsum += __shfl_down(dsum, off, 64);
  __shared__ float ws4[4];
  const int lane = t & 63, w = t >> 6;
  if (lane == 0) ws4[w] = dsum;
  __syncthreads();
  if (t == 0) {
    dpart[r] = ws4[0] + ws4[1] + ws4[2] + ws4[3];
    ppart[r] = d0 * d0;   // physics residual at n=0: u_t = du[r,0], frac_lap[0] = 0
  }
}

// Y[r,i] = sum_j du[r,j] * b[i-j]; fused epilogue: resid = u_t - COEF*Y, accumulate resid^2.
// 128x128 tile, BK=64, 4 waves, double-buffered LDS, XOR-swizzled quads, counted vmcnt.
// XCD-aware mapping: bid%8 lands on XCD bid%8 (round-robin heuristic); give each XCD
// 8 consecutive rb panels (2MB du) x all cb -> working set du-slice(2MB)+Mt(2MB) = L2 size.
// cb folded {0,1,2,3,7,6,5,4} so bid and bid+256 (same CU) have complementary work.
__launch_bounds__(256, 2)
__global__ void gemm(const __hip_bfloat16* __restrict__ du,
                     const __hip_bfloat16* __restrict__ Mt,
                     float* __restrict__ gpart) {
  __shared__ __hip_bfloat16 sA[2][8192];   // [128][64], quad-swizzled
  __shared__ __hip_bfloat16 sB[2][8192];
  __shared__ float wsum[4];

  const int t = threadIdx.x;
  const int w = t >> 6;
  const int lane = t & 63;

  const int bid = blockIdx.x;      // 0..511
  const int xcd = bid & 7;
  const int local = bid >> 3;      // 0..63
  const int rb = xcd * 8 + (local & 7);   // 0..63
  const int q = local >> 3;               // 0..7
  const int cb = (q < 4) ? q : 11 - q;    // {0,1,2,3,7,6,5,4}
  const int row0 = rb * 128;
  const int col0 = cb * 128;
  const int nkb = 2 * (cb + 1);    // K-blocks of 64 (triangular skip)

  const f32x4 vzero = {0.f, 0.f, 0.f, 0.f};
  f32x4 acc[4][4];
#pragma unroll
  for (int i = 0; i < 4; i++)
#pragma unroll
    for (int j = 0; j < 4; j++) acc[i][j] = vzero;

  // staging: thread t covers (row = t>>3, phys quad = t&7); source quad = phys ^ (row&7)
  const int srow = t >> 3;                       // 0..31
  const int scol = ((t & 7) ^ (srow & 7)) * 8;   // pre-swizzled source col (elements)
  const __hip_bfloat16* gA0 = du + (size_t)(row0 + srow) * 1024 + scol;
  const __hip_bfloat16* gB0 = Mt + (size_t)(col0 + srow) * 1024 + scol;

  auto stage = [&](int buf, int kb) {
    const int kc = kb * 64;
#pragma unroll
    for (int l = 0; l < 4; l++)
      load_lds16(gA0 + (size_t)l * 32 * 1024 + kc, (void*)&sA[buf][l * 2048 + t * 8]);
#pragma unroll
    for (int l = 0; l < 4; l++)
      load_lds16(gB0 + (size_t)l * 32 * 1024 + kc, (void*)&sB[buf][l * 2048 + t * 8]);
  };

  const int wm = w >> 1, wn = w & 1;
  const int frow = lane & 15;
  const int g4 = lane >> 4;              // logical k-quad 0..3
  const int ph0 = g4 ^ (frow & 7);       // ksub=0 physical quad

  auto compute = [&](int buf) {
#pragma unroll
    for (int ksub = 0; ksub < 2; ksub++) {
      const int ph = ph0 ^ (ksub << 2);  // ksub=1 -> logical quad +4
      bf16x8 aF[4], bF[4];
#pragma unroll
      for (int fm = 0; fm < 4; fm++)
        aF[fm] = *(const bf16x8*)&sA[buf][(wm * 64 + fm * 16 + frow) * 64 + ph * 8];
#pragma unroll
      for (int fn = 0; fn < 4; fn++)
        bF[fn] = *(const bf16x8*)&sB[buf][(wn * 64 + fn * 16 + frow) * 64 + ph * 8];
#pragma unroll
      for (int fm = 0; fm < 4; fm++)
#pragma unroll
        for (int fn = 0; fn < 4; fn++)
          acc[fm][fn] = __builtin_amdgcn_mfma_f32_16x16x32_bf16(aF[fm], bF[fn], acc[fm][fn], 0, 0, 0);
    }
  };

  stage(0, 0);
  for (int kb = 0; kb < nkb; kb++) {
    // BARRIER A: all waves done computing kb-1 (done reading buf kb+1&1) -> safe to overwrite
    asm volatile("" ::: "memory");
    __builtin_amdgcn_s_barrier();
    asm volatile("" ::: "memory");
    if (kb + 1 < nkb) {
      stage((kb + 1) & 1, kb + 1);                    // 8 loads in flight across barrier
      asm volatile("s_waitcnt vmcnt(8)" ::: "memory"); // cur tile's 8 (from kb-1) complete
    } else {
      asm volatile("s_waitcnt vmcnt(0)" ::: "memory"); // last tile: drain
    }
    // BARRIER B: every wave's cur loads complete
    __builtin_amdgcn_s_barrier();
    asm volatile("" ::: "memory");
    compute(kb & 1);
  }

  // fused epilogue: C/D layout col = lane&15, row = (lane>>4)*4 + reg  [HW-verified]
  float psum = 0.f;
  const int rbase = row0 + wm * 64 + (lane >> 4) * 4;
  const int ibase = col0 + wn * 64 + frow;
#pragma unroll
  for (int fm = 0; fm < 4; fm++) {
#pragma unroll
    for (int fn = 0; fn < 4; fn++) {
      const int icol = ibase + fn * 16;        // du index i; output position n = i+1
      if (icol < 1023) {
#pragma unroll
        for (int reg = 0; reg < 4; reg++) {
          const int r = rbase + fm * 16 + reg;
          float frac = COEF * acc[fm][fn][reg];
          float dui = __bfloat162float(du[(size_t)r * 1024 + icol]);
          float ut;
          if (icol == 1022) {
            ut = dui;                           // n = N-1 edge: u_t = du[N-2]
          } else {
            float dui1 = __bfloat162float(du[(size_t)r * 1024 + icol + 1]);
            ut = 0.5f * (dui + dui1);           // central difference
          }
          float res = ut - frac;
          psum += res * res;
        }
      }
    }
  }

#pragma unroll
  for (int off = 32; off > 0; off >>= 1) psum += __shfl_down(psum, off, 64);
  if (lane == 0) wsum[w] = psum;
  __syncthreads();
  if (t == 0) gpart[bid] = wsum[0] + wsum[1] + wsum[2] + wsum[3];
}

// Single-block tree reduction of all partials -> 3 outputs.
__global__ void finalize(const float* __restrict__ dpart, const float* __restrict__ ppart,
                         const float* __restrict__ gpart, float* __restrict__ out) {
  const int t = threadIdx.x;    // 256 threads
  float ds = 0.f, ps = 0.f;
  for (int i = t; i < 8192; i += 256) { ds += dpart[i]; ps += ppart[i]; }
  for (int i = t; i < 512; i += 256) ps += gpart[i];

#pragma unroll
  for (int off = 32; off > 0; off >>= 1) {
    ds += __shfl_down(ds, off, 64);
    ps += __shfl_down(ps, off, 64);
  }
  __shared__ float sd[4], sp[4];
  const int lane = t & 63, w = t >> 6;
  if (lane == 0) { sd[w] = ds; sp[w] = ps; }
  __syncthreads();
  if (t == 0) {
    float data = (sd[0] + sd[1] + sd[2] + sd[3]) * INV_COUNT;
    float phys = (sp[0] + sp[1] + sp[2] + sp[3]) * INV_COUNT;
    out[0] = data + 0.1f * phys;
    out[1] = data;
    out[2] = phys;
  }
}

extern "C" void kernel_launch(void* const* d_in, const int* in_sizes, int n_in,
                              void* d_out, int out_size, void* d_ws, size_t ws_size,
                              hipStream_t stream) {
  const float* u_pred = (const float*)d_in[0];
  const float* u_true = (const float*)d_in[1];
  float* out = (float*)d_out;

  char* ws = (char*)d_ws;
  float* dpart = (float*)ws;                                    // 8192 floats (32 KiB)
  float* ppart = (float*)(ws + 32768);                          // 8192 floats (32 KiB)
  float* gpart = (float*)(ws + 65536);                          // 512 floats (2 KiB)
  __hip_bfloat16* Mt = (__hip_bfloat16*)(ws + 131072);          // 1024*1024*2 = 2 MiB
  __hip_bfloat16* du = (__hip_bfloat16*)(ws + 131072 + 2097152);// 8192*1024*2 = 16 MiB

  prep<<<9216, 256, 0, stream>>>(u_pred, u_true, du, Mt, dpart, ppart);
  gemm<<<512, 256, 0, stream>>>(du, Mt, gpart);
  finalize<<<1, 256, 0, stream>>>(dpart, ppart, gpart, out);
}